// Round 1
// 370.425 us; speedup vs baseline: 1.1188x; 1.1188x over previous
//
#include <hip/hip_runtime.h>
#include <cfloat>
#include <math.h>

#define B_ 8
#define C_ 256
#define C2_ (C_/2)            // uints (bf16 pairs) per pixel
#define H_ 128
#define W_ 128
#define N_ (H_*W_)            // 16384
#define NRAND 32
#define NHARD 96
#define NPOS 256
#define INV_TEMP (1.0f/0.07f)

typedef __attribute__((ext_vector_type(8))) short short8;   // 8 bf16 (4 VGPRs)
typedef __attribute__((ext_vector_type(4))) float f32x4;    // MFMA acc

__device__ __forceinline__ unsigned bf16rne(float x) {
    unsigned u = __float_as_uint(x);
    return (u + 0x7FFFu + ((u >> 16) & 1u)) >> 16;
}
__device__ __forceinline__ float blo(unsigned w) { return __uint_as_float(w << 16); }
__device__ __forceinline__ float bhi(unsigned w) { return __uint_as_float(w & 0xFFFF0000u); }

// ---------------------------------------------------------------------------
// k1: normalize rgb along C, write transposed bf16 rgbT[b][n][c] (packed u32).
// (unchanged from previous round)
// ---------------------------------------------------------------------------
__global__ __launch_bounds__(256) void k1_rgb_norm_T(const float* __restrict__ rgb,
                                                     unsigned* __restrict__ rgbT) {
    __shared__ float tile[C_][67];
    __shared__ float redx[8][32], redy[8][32];
    __shared__ float invn[64];
    int bi = blockIdx.x;
    int b  = bi >> 8;                 // 256 tiles per batch
    int p0 = (bi & 255) << 6;
    int t  = threadIdx.x;
    int pxh = t & 31;                 // float2 pixel-pair index
    int cg  = t >> 5;                 // 0..7
    const float2* src2 = (const float2*)(rgb + (size_t)b * C_ * N_);
    float ssx = 0.f, ssy = 0.f;
    #pragma unroll 4
    for (int p = 0; p < 32; ++p) {
        int c = p * 8 + cg;
        float2 v = src2[(size_t)c * (N_ / 2) + (p0 >> 1) + pxh];
        tile[c][2 * pxh]     = v.x;
        tile[c][2 * pxh + 1] = v.y;
        ssx += v.x * v.x;
        ssy += v.y * v.y;
    }
    redx[cg][pxh] = ssx; redy[cg][pxh] = ssy;
    __syncthreads();
    if (t < 32) {
        float sx = 0.f, sy = 0.f;
        #pragma unroll
        for (int g2 = 0; g2 < 8; ++g2) { sx += redx[g2][t]; sy += redy[g2][t]; }
        invn[2 * t]     = 1.0f / fmaxf(sqrtf(sx), 1e-12f);
        invn[2 * t + 1] = 1.0f / fmaxf(sqrtf(sy), 1e-12f);
    }
    __syncthreads();
    unsigned* dst = rgbT + (size_t)(b * N_ + p0) * C2_;
    int u  = t & 127;                 // uint (channel-pair) index
    int ph = t >> 7;
    #pragma unroll 4
    for (int it = 0; it < 32; ++it) {
        int px = ph + 2 * it;
        float sc = invn[px];
        unsigned pa = bf16rne(tile[2 * u][px] * sc);
        unsigned pb = bf16rne(tile[2 * u + 1][px] * sc);
        dst[(size_t)px * C2_ + u] = pa | (pb << 16);
    }
}

// ---------------------------------------------------------------------------
// k2: per 64-pixel tile.
//  - dep staged as bf16 [px][256ch] in LDS, chunk-XOR-swizzled (c8 ^ (px&7)).
//  - 32 rand rgb vectors staged bf16 [n][256ch], same swizzle.
//  - rand sims via MFMA 16x16x32 bf16: wave w owns px rows [16w,16w+16) x 32 rand
//    (2 N-tiles, 8 K-steps = 16 MFMA/wave). Raw sims dumped to LDS (reusing the
//    rand region), scaled by fp32 invn*INV_TEMP in the quad epilogue.
//  - pos bilinear stays VALU: thread (px,g) dots bf16 dep row vs gathered nbr.
//  - blocks on grid rows (y%8==0) also emit normalized bf16 dep vectors for the
//    8 grid pixels -> depG, consumed by k3.
// ---------------------------------------------------------------------------
__global__ __launch_bounds__(256) void k2_main(
        const float* __restrict__ dep, const unsigned* __restrict__ rgbT,
        const float* __restrict__ coords, const int* __restrict__ rand_idx,
        float* __restrict__ lse_base, float* __restrict__ pos_out,
        float* __restrict__ maxneg_out, unsigned* __restrict__ depG) {
    __shared__ __align__(16) uint4 dep4[64 * 32];   // 32 KB bf16 [px][ch], swizzled
    __shared__ __align__(16) uint4 rs4[32 * 32];    // 16 KB rand bf16 / later sims f32[64][32]
    __shared__ float red[4][64];
    __shared__ float invn[64];
    int bi = blockIdx.x;
    int b  = bi >> 8;
    int p0 = (bi & 255) << 6;
    int t  = threadIdx.x;
    int lane = t & 63, w = t >> 6;

    // ---- stage 32 rand vectors: 16B gather chunks, coalesced 512B per vector
    #pragma unroll
    for (int it = 0; it < 4; ++it) {
        int flat = it * 256 + t;
        int rn = flat >> 5, c8 = flat & 31;
        int idx = rand_idx[b * NRAND + rn];
        const uint4* src = (const uint4*)(rgbT + (size_t)(b * N_ + idx) * C2_);
        rs4[rn * 32 + (c8 ^ (rn & 7))] = src[c8];
    }

    // ---- stage dep: thread -> pixel p0+lane, channels [64w, 64w+64)
    const float* depb = dep + (size_t)b * C_ * N_ + p0 + lane;
    float ssq = 0.f;
    int psw = lane & 7;
    #pragma unroll 2
    for (int i = 0; i < 8; ++i) {
        int c0 = w * 64 + i * 8;
        float v[8];
        #pragma unroll
        for (int k = 0; k < 8; ++k) {
            v[k] = depb[(size_t)(c0 + k) * N_];
            ssq += v[k] * v[k];
        }
        uint4 q;
        q.x = bf16rne(v[0]) | (bf16rne(v[1]) << 16);
        q.y = bf16rne(v[2]) | (bf16rne(v[3]) << 16);
        q.z = bf16rne(v[4]) | (bf16rne(v[5]) << 16);
        q.w = bf16rne(v[6]) | (bf16rne(v[7]) << 16);
        dep4[lane * 32 + ((w * 8 + i) ^ psw)] = q;
    }
    red[w][lane] = ssq;

    // ---- bilinear setup (issue coord loads before the barrier)
    int px = t >> 2, g = t & 3;
    int n  = p0 + px;
    float xf = coords[(size_t)b * 2 * N_ + n];
    float yf = coords[(size_t)b * 2 * N_ + N_ + n];
    float x0 = floorf(xf), y0 = floorf(yf);
    float wx = xf - x0, wy = yf - y0;
    int ix = (int)x0 + (g & 1);
    int iy = (int)y0 + (g >> 1);
    float wgt = ((g & 1) ? wx : 1.f - wx) * ((g & 2) ? wy : 1.f - wy);
    if (ix < 0 || ix >= W_ || iy < 0 || iy >= H_) wgt = 0.f;
    int ixc = min(max(ix, 0), W_ - 1), iyc = min(max(iy, 0), H_ - 1);
    const uint4* nbr4 = (const uint4*)(rgbT + (size_t)(b * N_ + iyc * W_ + ixc) * C2_);

    __syncthreads();                          // all LDS staged
    if (t < 64) {
        float s = red[0][t] + red[1][t] + red[2][t] + red[3][t];
        invn[t] = 1.0f / fmaxf(sqrtf(s), 1e-12f);
    }

    // ---- MFMA: A = dep rows (M=px), B = rand vectors (N=rand), K=256
    // lane l: A[w*16 + (l&15)][k = 32kc + (l>>4)*8 + 0..7], B analogous.
    f32x4 acc0 = {0.f, 0.f, 0.f, 0.f};
    f32x4 acc1 = {0.f, 0.f, 0.f, 0.f};
    int l15 = lane & 15, l4 = lane >> 4;
    int pxA = (w << 4) + l15;
    const short8* lds8 = (const short8*)dep4;
    const short8* rnd8 = (const short8*)rs4;
    #pragma unroll
    for (int kc = 0; kc < 8; ++kc) {
        int c8 = kc * 4 + l4;
        short8 a  = lds8[pxA * 32 + (c8 ^ (pxA & 7))];
        short8 b0 = rnd8[l15 * 32 + (c8 ^ (l15 & 7))];
        short8 b1 = rnd8[(16 + l15) * 32 + (c8 ^ (l15 & 7))];
        acc0 = __builtin_amdgcn_mfma_f32_16x16x32_bf16(a, b0, acc0, 0, 0, 0);
        acc1 = __builtin_amdgcn_mfma_f32_16x16x32_bf16(a, b1, acc1, 0, 0, 0);
    }

    // ---- pos: dot(dep_px, nbr_g) on VALU (bf16 unpack)
    float accN = 0.f;
    const uint4* drow = dep4 + (size_t)px * 32;
    int dsw = px & 7;
    #pragma unroll 4
    for (int c8 = 0; c8 < 32; ++c8) {
        uint4 dq = drow[c8 ^ dsw];
        uint4 rq = nbr4[c8];
        accN += blo(dq.x) * blo(rq.x) + bhi(dq.x) * bhi(rq.x)
              + blo(dq.y) * blo(rq.y) + bhi(dq.y) * bhi(rq.y)
              + blo(dq.z) * blo(rq.z) + bhi(dq.z) * bhi(rq.z)
              + blo(dq.w) * blo(rq.w) + bhi(dq.w) * bhi(rq.w);
    }
    __syncthreads();                          // MFMA+pos reads done; rs4 reusable

    // ---- dump raw sims -> rs4 as f32 [64][32], n-index XOR'd by (prow&3)<<2
    // D layout: row(M=px) = (l>>4)*4 + reg, col(N=rand) = l&15  [guide §3, m89]
    float* simsF = (float*)rs4;
    #pragma unroll
    for (int r = 0; r < 4; ++r) {
        int prow = (w << 4) + (l4 << 2) + r;   // prow&3 == r
        int swn = r << 2;
        simsF[prow * 32 + (l15 ^ swn)]        = acc0[r];
        simsF[prow * 32 + (16 + (l15 ^ swn))] = acc1[r];
    }
    __syncthreads();

    // ---- epilogue per (px, g): thread g owns rand [8g, 8g+8)
    float scale = invn[px] * INV_TEMP;
    float pp = accN * wgt;
    pp += __shfl_xor(pp, 1, 4);
    pp += __shfl_xor(pp, 2, 4);
    float pos = pp * scale;
    const float4* sf = (const float4*)simsF;
    int fsw = px & 3;
    float4 ra = sf[px * 8 + ((g * 2) ^ fsw)];
    float4 rb = sf[px * 8 + (((g * 2) ^ fsw) ^ 1)];
    float r[8] = {ra.x, ra.y, ra.z, ra.w, rb.x, rb.y, rb.z, rb.w};
    float ml = -FLT_MAX;
    #pragma unroll
    for (int j = 0; j < 8; ++j) { r[j] *= scale; ml = fmaxf(ml, r[j]); }
    ml = fmaxf(ml, __shfl_xor(ml, 1, 4));
    ml = fmaxf(ml, __shfl_xor(ml, 2, 4));
    float mneg = ml;
    float mall = fmaxf(mneg, pos);
    float se = 0.f;
    #pragma unroll
    for (int j = 0; j < 8; ++j) se += expf(r[j] - mall);
    se += __shfl_xor(se, 1, 4);
    se += __shfl_xor(se, 2, 4);
    if (g == 0) {
        float lse = mall + logf(se + expf(pos - mall));
        size_t o = (size_t)b * N_ + n;
        lse_base[o]   = lse;
        pos_out[o]    = pos;
        maxneg_out[o] = mneg;
    }

    // ---- depG: normalized bf16 dep vectors for the 8 grid pixels of this tile
    int y = p0 >> 7;                  // 64-px tile = half a row -> y uniform
    if ((y & 7) == 0) {
        int m = t >> 5, u = t & 31;
        int gpx = m * 8;              // grid pixels at px = 0,8,...,56
        int gx  = (p0 & 127) + gpx;
        int p   = ((y >> 3) << 4) + (gx >> 3);
        float sc = invn[gpx];
        const unsigned* srow = (const unsigned*)(dep4 + (size_t)gpx * 32);
        int xsw = (gpx & 7) << 2;     // chunk-swizzle expressed in u32 units
        unsigned* dst = depG + (size_t)((b << 8) + p) * 128;
        #pragma unroll
        for (int it = 0; it < 4; ++it) {
            int uu = u + it * 32;
            unsigned wv = srow[uu ^ xsw];
            dst[uu] = bf16rne(blo(wv) * sc) | (bf16rne(bhi(wv) * sc) << 16);
        }
    }
}

// ---------------------------------------------------------------------------
// k3: hard negatives. One block per (b, grid-point p): 96 hard sims,
// logsumexp + max. dep vector now comes pre-normalized from depG (one
// coalesced 512B row) instead of a 256-line strided column + norm reduce.
// ---------------------------------------------------------------------------
__global__ __launch_bounds__(128) void k3_hard(
        const unsigned* __restrict__ depG, const unsigned* __restrict__ rgbT,
        const float* __restrict__ coords, const int* __restrict__ hoffu,
        const int* __restrict__ hoffv, float* __restrict__ lse_hard,
        float* __restrict__ max_hard) {
    __shared__ __align__(16) float dv[256];
    __shared__ float sm_[2], ss_[2];
    int bp = blockIdx.x;
    int b = bp >> 8, p = bp & 255;
    int gy = (p >> 4) * 8, gx = (p & 15) * 8;
    int nn = gy * W_ + gx;
    int t  = threadIdx.x;
    unsigned wv = depG[(size_t)bp * 128 + t];
    dv[2 * t]     = blo(wv);
    dv[2 * t + 1] = bhi(wv);
    float pu = coords[(size_t)b * 2 * N_ + nn];
    float pv = coords[(size_t)b * 2 * N_ + N_ + nn];
    int iu = (int)fminf(fmaxf(pu, 0.f), (float)(W_ - 1));
    int iv = (int)fminf(fmaxf(pv, 0.f), (float)(H_ - 1));
    float sim = -FLT_MAX;
    int ou = 0, ov = 0;
    if (t < NHARD) {
        ou = hoffu[((size_t)b * NHARD + t) * NPOS + p];
        ov = hoffv[((size_t)b * NHARD + t) * NPOS + p];
    }
    __syncthreads();
    if (t < NHARD) {
        if (ou == 0 && ov == 0) ou = 1;
        int hu = min(max(iu + ou, 0), W_ - 1);
        int hv = min(max(iv + ov, 0), H_ - 1);
        const uint4* hvec = (const uint4*)(rgbT + (size_t)(b * N_ + hv * W_ + hu) * C2_);
        float acc = 0.f;
        #pragma unroll 4
        for (int c8 = 0; c8 < 32; ++c8) {
            uint4 q = hvec[c8];
            float4 d0 = *(const float4*)(&dv[c8 * 8]);
            float4 d1 = *(const float4*)(&dv[c8 * 8 + 4]);
            acc += d0.x * blo(q.x) + d0.y * bhi(q.x)
                 + d0.z * blo(q.y) + d0.w * bhi(q.y)
                 + d1.x * blo(q.z) + d1.y * bhi(q.z)
                 + d1.z * blo(q.w) + d1.w * bhi(q.w);
        }
        sim = acc * INV_TEMP;
    }
    float m = sim;
    #pragma unroll
    for (int o = 32; o > 0; o >>= 1) m = fmaxf(m, __shfl_down(m, o, 64));
    int wid = t >> 6;
    if ((t & 63) == 0) sm_[wid] = m;
    __syncthreads();
    float mm = fmaxf(sm_[0], sm_[1]);
    float e = (t < NHARD) ? expf(sim - mm) : 0.f;
    #pragma unroll
    for (int o = 32; o > 0; o >>= 1) e += __shfl_down(e, o, 64);
    if ((t & 63) == 0) ss_[wid] = e;
    __syncthreads();
    if (t == 0) {
        lse_hard[bp] = mm + logf(ss_[0] + ss_[1]);
        max_hard[bp] = mm;
    }
}

// ---------------------------------------------------------------------------
// k4: masked reduction over all pixels (with grid-point hard fix-up).
// ---------------------------------------------------------------------------
__global__ __launch_bounds__(256) void k4_reduce(
        const float* __restrict__ lse_base, const float* __restrict__ pos_sim,
        const float* __restrict__ max_neg, const float* __restrict__ mask,
        const float* __restrict__ lse_hard, const float* __restrict__ max_hard,
        float* __restrict__ acc) {
    int i = blockIdx.x * 256 + threadIdx.x;
    float l  = lse_base[i], ps = pos_sim[i], mn = max_neg[i], mk = mask[i];
    int b = i >> 14;
    int n = i & (N_ - 1);
    int y = n >> 7, x = n & 127;
    if (((y & 7) | (x & 7)) == 0) {
        int p = ((y >> 3) << 4) + (x >> 3);
        float lh = lse_hard[(b << 8) + p];
        float mh = max_hard[(b << 8) + p];
        float m = fmaxf(l, lh);
        l  = m + logf(expf(l - m) + expf(lh - m));
        mn = fmaxf(mn, mh);
    }
    float s0 = (l - ps) * mk;
    float s1 = (ps > mn && mk > 0.5f) ? 1.f : 0.f;
    float s2 = mk;
    #pragma unroll
    for (int o = 32; o > 0; o >>= 1) {
        s0 += __shfl_down(s0, o, 64);
        s1 += __shfl_down(s1, o, 64);
        s2 += __shfl_down(s2, o, 64);
    }
    __shared__ float r0[4], r1[4], r2[4];
    int wid = threadIdx.x >> 6;
    if ((threadIdx.x & 63) == 0) { r0[wid] = s0; r1[wid] = s1; r2[wid] = s2; }
    __syncthreads();
    if (threadIdx.x == 0) {
        atomicAdd(&acc[0], r0[0] + r0[1] + r0[2] + r0[3]);
        atomicAdd(&acc[1], r1[0] + r1[1] + r1[2] + r1[3]);
        atomicAdd(&acc[2], r2[0] + r2[1] + r2[2] + r2[3]);
    }
}

__global__ void k5_final(const float* __restrict__ acc, float* __restrict__ out) {
    if (threadIdx.x == 0) {
        float denom = fmaxf(acc[2], 1.0f);
        out[0] = acc[0] / denom;
        out[1] = acc[1] / denom * 100.0f;
    }
}

extern "C" void kernel_launch(void* const* d_in, const int* in_sizes, int n_in,
                              void* d_out, int out_size, void* d_ws, size_t ws_size,
                              hipStream_t stream) {
    const float* rgb     = (const float*)d_in[0];
    const float* dep     = (const float*)d_in[1];
    const float* coords  = (const float*)d_in[2];
    const float* mask    = (const float*)d_in[3];
    const int*   rand_i  = (const int*)d_in[4];
    const int*   hoffu   = (const int*)d_in[5];
    const int*   hoffv   = (const int*)d_in[6];
    float* out = (float*)d_out;
    char*  ws  = (char*)d_ws;

    const size_t RGBT_B = (size_t)B_ * N_ * C_ * 2;      // bf16: 67108864 B
    const size_t PIX_B  = (size_t)B_ * N_ * 4;           // 524288 B
    unsigned* rgbT  = (unsigned*)ws;
    float* lse_base = (float*)(ws + RGBT_B);
    float* pos_sim  = (float*)(ws + RGBT_B + PIX_B);
    float* max_neg  = (float*)(ws + RGBT_B + 2 * PIX_B);
    float* lse_hard = (float*)(ws + RGBT_B + 3 * PIX_B);
    float* max_hard = (float*)(ws + RGBT_B + 3 * PIX_B + 8192);
    float* acc      = (float*)(ws + RGBT_B + 3 * PIX_B + 2 * 8192);
    unsigned* depG  = (unsigned*)(ws + RGBT_B + 3 * PIX_B + 2 * 8192 + 1024); // 1 MB

    hipMemsetAsync(acc, 0, 16, stream);
    k1_rgb_norm_T<<<B_ * (N_ / 64), 256, 0, stream>>>(rgb, rgbT);
    k2_main<<<B_ * (N_ / 64), 256, 0, stream>>>(dep, rgbT, coords, rand_i,
                                                lse_base, pos_sim, max_neg, depG);
    k3_hard<<<B_ * NPOS, 128, 0, stream>>>(depG, rgbT, coords, hoffu, hoffv,
                                           lse_hard, max_hard);
    k4_reduce<<<(B_ * N_) / 256, 256, 0, stream>>>(lse_base, pos_sim, max_neg,
                                                   mask, lse_hard, max_hard, acc);
    k5_final<<<1, 64, 0, stream>>>(acc, out);
}